// Round 1
// baseline (1032.045 us; speedup 1.0000x reference)
//
#include <hip/hip_runtime.h>
#include <hip/hip_bf16.h>
#include <stdint.h>

#define D 256
#define NBUCK 391            // ceil(100000 / 256) buckets of 256 nodes
#define BSHIFT 8
#define TILE 4096            // edges per block in binning pass

typedef short short8 __attribute__((ext_vector_type(8)));
typedef float f32x4 __attribute__((ext_vector_type(4)));
typedef float f32x2 __attribute__((ext_vector_type(2)));

__device__ __forceinline__ float bf2f(unsigned short u) {
  return __uint_as_float(((unsigned)u) << 16);
}
__device__ __forceinline__ unsigned short f2bf(float f) {
  unsigned u = __float_as_uint(f);
  unsigned r = u + 0x7FFFu + ((u >> 16) & 1u);
  return (unsigned short)(r >> 16);
}

// ---------------- K1: coarse bucket histogram (LDS-binned) ----------------
__global__ void bucket_hist_kernel(const int* __restrict__ src, int* __restrict__ bcount, int E) {
  __shared__ int h[NBUCK];
  for (int i = threadIdx.x; i < NBUCK; i += 256) h[i] = 0;
  __syncthreads();
  int gid = blockIdx.x * 256 + threadIdx.x;
  for (int e = gid; e < E; e += 256 * 256) atomicAdd(&h[src[e] >> BSHIFT], 1);
  __syncthreads();
  for (int i = threadIdx.x; i < NBUCK; i += 256) {
    int c = h[i];
    if (c) atomicAdd(&bcount[i], c);
  }
}

// ---------------- K2: exclusive scan of bucket counts ----------------
__global__ void bucket_scan_kernel(const int* __restrict__ bcount, int* __restrict__ bbase,
                                   int* __restrict__ gcursor) {
  __shared__ int sc[2][512];
  int tid = threadIdx.x;
  sc[0][tid] = (tid < NBUCK) ? bcount[tid] : 0;
  __syncthreads();
  int d = 0;
  for (int off = 1; off < 512; off <<= 1) {
    int v = sc[d][tid];
    if (tid >= off) v += sc[d][tid - off];
    sc[d ^ 1][tid] = v;
    __syncthreads();
    d ^= 1;
  }
  if (tid < NBUCK) {
    int excl = (tid == 0) ? 0 : sc[d][tid - 1];
    bbase[tid] = excl;
    gcursor[tid] = excl;
  }
}

// ---------------- K3: binning scatter ----------------
__launch_bounds__(256)
__global__ void binscatter_kernel(const int* __restrict__ src, const int* __restrict__ dst,
                                  int* __restrict__ gcursor, int* __restrict__ ebuf, int E) {
  __shared__ int hist[NBUCK];
  __shared__ int lstart[512];
  __shared__ int gbase[NBUCK];
  __shared__ int sc[2][512];
  __shared__ int stag[TILE];
  __shared__ unsigned short sbuck[TILE];

  int tid = threadIdx.x;
  int base = blockIdx.x * TILE;
  int tilecount = E - base;
  if (tilecount > TILE) tilecount = TILE;

  for (int i = tid; i < NBUCK; i += 256) hist[i] = 0;
  __syncthreads();

  int esrc[16], edst[16];
#pragma unroll
  for (int k = 0; k < 16; k++) {
    int e = base + k * 256 + tid;
    if (e < E) {
      esrc[k] = src[e];
      edst[k] = dst[e];
      atomicAdd(&hist[esrc[k] >> BSHIFT], 1);
    } else {
      esrc[k] = -1;
      edst[k] = 0;
    }
  }
  __syncthreads();

  for (int i = tid; i < 512; i += 256) sc[0][i] = (i < NBUCK) ? hist[i] : 0;
  __syncthreads();
  int d = 0;
  for (int off = 1; off < 512; off <<= 1) {
    for (int i = tid; i < 512; i += 256) {
      int v = sc[d][i];
      if (i >= off) v += sc[d][i - off];
      sc[d ^ 1][i] = v;
    }
    __syncthreads();
    d ^= 1;
  }
  for (int i = tid; i < 512; i += 256) lstart[i] = (i == 0) ? 0 : sc[d][i - 1];
  __syncthreads();

  for (int b = tid; b < NBUCK; b += 256) {
    int c = hist[b];
    if (c) gbase[b] = atomicAdd(&gcursor[b], c);
  }
  __syncthreads();

  for (int i = tid; i < NBUCK; i += 256) hist[i] = 0;
  __syncthreads();

#pragma unroll
  for (int k = 0; k < 16; k++) {
    if (esrc[k] >= 0) {
      int b = esrc[k] >> BSHIFT;
      int r = atomicAdd(&hist[b], 1);
      int pos = lstart[b] + r;
      stag[pos] = edst[k] | ((esrc[k] & 255) << 20);
      sbuck[pos] = (unsigned short)b;
    }
  }
  __syncthreads();

  for (int s = tid; s < tilecount; s += 256) {
    int b = sbuck[s];
    ebuf[gbase[b] + (s - lstart[b])] = stag[s];
  }
}

// ---------------- K4: per-bucket counting sort ----------------
__launch_bounds__(256)
__global__ void bucketsort_kernel(const int* __restrict__ ebuf, const int* __restrict__ bbase,
                                  const int* __restrict__ bcount, int* __restrict__ csr,
                                  int* __restrict__ offsets, int* __restrict__ ecount,
                                  float* __restrict__ rnorm, int N) {
  __shared__ int ncnt[256];
  __shared__ int nstart[256];
  __shared__ int sc[2][256];
  int tid = threadIdx.x;
  int b = blockIdx.x;
  int base = bbase[b];
  int cnt = bcount[b];
  int node0 = b << BSHIFT;

  ncnt[tid] = 0;
  __syncthreads();
  for (int s = tid; s < cnt; s += 256) {
    int v = ebuf[base + s];
    atomicAdd(&ncnt[v >> 20], 1);
  }
  __syncthreads();

  int mycnt = ncnt[tid];
  sc[0][tid] = mycnt;
  __syncthreads();
  int d = 0;
  for (int off = 1; off < 256; off <<= 1) {
    int v = sc[d][tid];
    if (tid >= off) v += sc[d][tid - off];
    sc[d ^ 1][tid] = v;
    __syncthreads();
    d ^= 1;
  }
  nstart[tid] = (tid == 0) ? 0 : sc[d][tid - 1];
  __syncthreads();

  int node = node0 + tid;
  if (node < N) {
    offsets[node] = base + nstart[tid];
    ecount[node] = mycnt;
    rnorm[node] = rsqrtf((float)(mycnt + 1));
  }

  ncnt[tid] = 0;
  __syncthreads();
  for (int s = tid; s < cnt; s += 256) {
    int v = ebuf[base + s];
    int nl = v >> 20;
    int r = atomicAdd(&ncnt[nl], 1);
    csr[base + nstart[nl] + r] = v & 0xFFFFF;
  }
}

// ---------------- fp32 -> bf16 conversions ----------------
__global__ void convx_kernel(const float* __restrict__ x, unsigned short* __restrict__ xb,
                             int n, int npad) {
  int i4 = blockIdx.x * 256 + threadIdx.x;
  long long elem = (long long)i4 * 4;
  if (elem >= (long long)npad * D) return;
  int row = (int)(elem / D);
  ushort4 o;
  if (row < n) {
    const float4 v = *(const float4*)&x[elem];
    o.x = f2bf(v.x); o.y = f2bf(v.y); o.z = f2bf(v.z); o.w = f2bf(v.w);
  } else {
    o = make_ushort4(0, 0, 0, 0);
  }
  *(ushort4*)&xb[elem] = o;
}

__global__ void convw_kernel(const float* __restrict__ w, unsigned short* __restrict__ wb) {
  int i4 = blockIdx.x * 256 + threadIdx.x;
  int elem = i4 * 4;
  const float4 v = *(const float4*)&w[elem];
  ushort4 o;
  o.x = f2bf(v.x); o.y = f2bf(v.y); o.z = f2bf(v.z); o.w = f2bf(v.w);
  *(ushort4*)&wb[elem] = o;
}

// ---------------- bf16 MFMA GEMM: hs = rsqrt(deg) * (x @ W^T) ----------------
// Output written in COLUMN-BLOCKED layout: hsb[cb][row][c] with cb = col>>4,
// c = col&15. One 16-col slice = npad*32 B = 3.2 MB -> fits a 4 MB per-XCD L2.
__launch_bounds__(256)
__global__ void gemm_kernel(const unsigned short* __restrict__ A,
                            const unsigned short* __restrict__ B,
                            unsigned short* __restrict__ Hout,
                            const float* __restrict__ rnorm, int n, int npad) {
  __shared__ unsigned short sA[128 * 32];
  __shared__ unsigned short sB[128 * 32];
  int tid = threadIdx.x;
  int wave = tid >> 6, lane = tid & 63;
  int wm = wave >> 1, wn = wave & 1;
  int l16 = lane & 15, quad = lane >> 4;
  int arow0 = blockIdx.x * 128;
  int brow0 = blockIdx.y * 128;

  f32x4 acc[4][4];
  const f32x4 zero = {0.f, 0.f, 0.f, 0.f};
#pragma unroll
  for (int i = 0; i < 4; i++)
#pragma unroll
    for (int j = 0; j < 4; j++) acc[i][j] = zero;

  for (int k0 = 0; k0 < 256; k0 += 32) {
#pragma unroll
    for (int it = 0; it < 2; ++it) {
      int c = it * 256 + tid;
      int row = c >> 2, cc = (c & 3) * 8;
      *(int4*)&sA[c * 8] = *(const int4*)&A[(arow0 + row) * 256 + k0 + cc];
      *(int4*)&sB[c * 8] = *(const int4*)&B[(brow0 + row) * 256 + k0 + cc];
    }
    __syncthreads();
    short8 af[4], bfr[4];
#pragma unroll
    for (int i = 0; i < 4; i++)
      af[i] = *(const short8*)&sA[(wm * 64 + i * 16 + l16) * 32 + quad * 8];
#pragma unroll
    for (int j = 0; j < 4; j++)
      bfr[j] = *(const short8*)&sB[(wn * 64 + j * 16 + l16) * 32 + quad * 8];
#pragma unroll
    for (int i = 0; i < 4; i++)
#pragma unroll
      for (int j = 0; j < 4; j++)
        acc[i][j] = __builtin_amdgcn_mfma_f32_16x16x32_bf16(af[i], bfr[j], acc[i][j], 0, 0, 0);
    __syncthreads();
  }

  int cbbase = (brow0 >> 4) + wn * 4;
#pragma unroll
  for (int i = 0; i < 4; i++) {
    int rowb = arow0 + wm * 64 + i * 16 + quad * 4;
#pragma unroll
    for (int r = 0; r < 4; r++) {
      int gr = rowb + r;
      float rn = (gr < n) ? rnorm[gr] : 0.f;
#pragma unroll
      for (int j = 0; j < 4; j++) {
        Hout[((size_t)(cbbase + j) * npad + gr) * 16 + l16] = f2bf(acc[i][j][r] * rn);
      }
    }
  }
}

// ---------------- phased CSR gather: one 16-col slice per XCD ----------------
// phase = blockIdx.x & 7 -> XCD id (round-robin heuristic). XCD p only ever
// touches slice (pbase+p) = 3.2 MB, which stays L2-resident for the launch.
// Wave layout: 8 lanes per edge (32 B slice read), 8 edges per load inst,
// 8 nodes per wave; csr/metadata/output are nontemporal so they don't evict
// the pinned slice.
__launch_bounds__(256)
__global__ void gather_phase_kernel(const unsigned short* __restrict__ hsb,
                                    const int* __restrict__ offsets,
                                    const int* __restrict__ ecount,
                                    const float* __restrict__ rnorm,
                                    const int* __restrict__ csr,
                                    float* __restrict__ out,
                                    int n, int npad, int pbase) {
  const int wave = threadIdx.x >> 6;
  const int lane = threadIdx.x & 63;
  const int phase = blockIdx.x & 7;
  const int grp = blockIdx.x >> 3;
  const int cb = pbase + phase;
  const int g = lane >> 3;   // edge slot 0..7
  const int c = lane & 7;    // col pair 0..7 within 16-col slice
  const unsigned short* slice = hsb + (size_t)cb * npad * 16;

  int node0 = grp * 32 + wave * 8;
#pragma unroll 1
  for (int ni = 0; ni < 8; ++ni) {
    int node = node0 + ni;
    if (node >= n) break;
    int start = __builtin_nontemporal_load(&offsets[node]);
    int cnt = __builtin_nontemporal_load(&ecount[node]);
    float a0 = 0.f, a1 = 0.f;
    for (int base = 0; base < cnt; base += 64) {
      int m = cnt - base;
      if (m > 64) m = 64;
      int idxv = 0;
      if (lane < m) idxv = __builtin_nontemporal_load(&csr[start + base + lane]);
      int t = 0;
      for (; t + 32 <= m; t += 32) {
        int d0 = __shfl(idxv, t + g);
        int d1 = __shfl(idxv, t + 8 + g);
        int d2 = __shfl(idxv, t + 16 + g);
        int d3 = __shfl(idxv, t + 24 + g);
        unsigned u0 = *(const unsigned*)&slice[d0 * 16 + c * 2];
        unsigned u1 = *(const unsigned*)&slice[d1 * 16 + c * 2];
        unsigned u2 = *(const unsigned*)&slice[d2 * 16 + c * 2];
        unsigned u3 = *(const unsigned*)&slice[d3 * 16 + c * 2];
        a0 += bf2f((unsigned short)u0) + bf2f((unsigned short)u1) +
              bf2f((unsigned short)u2) + bf2f((unsigned short)u3);
        a1 += bf2f((unsigned short)(u0 >> 16)) + bf2f((unsigned short)(u1 >> 16)) +
              bf2f((unsigned short)(u2 >> 16)) + bf2f((unsigned short)(u3 >> 16));
      }
      for (; t + 8 <= m; t += 8) {
        int d0 = __shfl(idxv, t + g);
        unsigned u0 = *(const unsigned*)&slice[d0 * 16 + c * 2];
        a0 += bf2f((unsigned short)u0);
        a1 += bf2f((unsigned short)(u0 >> 16));
      }
      if (t < m) {
        int d0 = __shfl(idxv, t + g);
        unsigned u0 = 0;
        if (g < m - t) u0 = *(const unsigned*)&slice[d0 * 16 + c * 2];
        a0 += bf2f((unsigned short)u0);
        a1 += bf2f((unsigned short)(u0 >> 16));
      }
    }
    // reduce across the 8 edge slots (lanes differing in bits 3..5)
    a0 += __shfl_xor(a0, 8);  a1 += __shfl_xor(a1, 8);
    a0 += __shfl_xor(a0, 16); a1 += __shfl_xor(a1, 16);
    a0 += __shfl_xor(a0, 32); a1 += __shfl_xor(a1, 32);
    if (g == 0) {
      unsigned us = *(const unsigned*)&slice[node * 16 + c * 2];
      float rn = rnorm[node];
      f32x2 o;
      o.x = rn * (a0 + bf2f((unsigned short)us));
      o.y = rn * (a1 + bf2f((unsigned short)(us >> 16)));
      __builtin_nontemporal_store(o, (f32x2*)&out[(size_t)node * 256 + cb * 16 + c * 2]);
    }
  }
}

extern "C" void kernel_launch(void* const* d_in, const int* in_sizes, int n_in,
                              void* d_out, int out_size, void* d_ws, size_t ws_size,
                              hipStream_t stream) {
  const float* x = (const float*)d_in[0];
  const float* W = (const float*)d_in[1];
  const int* ei = (const int*)d_in[2];
  float* out = (float*)d_out;

  int N = in_sizes[0] / D;        // 100000
  int E = in_sizes[2] / 2;        // 3200000
  int NPAD = (N + 127) & ~127;
  const int* src = ei;
  const int* dst = ei + E;

  char* p = (char*)d_ws;
  auto alloc = [&](size_t b) {
    char* r = p;
    p += (b + 255) & ~(size_t)255;
    return r;
  };
  unsigned short* xb = (unsigned short*)alloc((size_t)NPAD * D * 2);
  unsigned short* wb = (unsigned short*)alloc((size_t)D * D * 2);
  unsigned short* hb = (unsigned short*)alloc((size_t)NPAD * D * 2);
  int* csr = (int*)alloc((size_t)E * 4);
  int* offsets = (int*)alloc((size_t)N * 4);
  int* ecount = (int*)alloc((size_t)N * 4);
  float* rnorm = (float*)alloc((size_t)N * 4);
  int* bcount = (int*)alloc(NBUCK * 4);
  int* bbase = (int*)alloc(NBUCK * 4);
  int* gcursor = (int*)alloc(NBUCK * 4);
  // ebuf (E*4 = 12.8 MB) aliases hb (51 MB): dead before gemm writes hb
  int* ebuf = (int*)hb;

  hipMemsetAsync(bcount, 0, NBUCK * 4, stream);
  bucket_hist_kernel<<<256, 256, 0, stream>>>(src, bcount, E);
  bucket_scan_kernel<<<1, 512, 0, stream>>>(bcount, bbase, gcursor);
  binscatter_kernel<<<(E + TILE - 1) / TILE, 256, 0, stream>>>(src, dst, gcursor, ebuf, E);
  bucketsort_kernel<<<NBUCK, 256, 0, stream>>>(ebuf, bbase, bcount, csr, offsets, ecount, rnorm, N);
  convx_kernel<<<(NPAD * (D / 4) + 255) / 256, 256, 0, stream>>>(x, xb, N, NPAD);
  convw_kernel<<<(D * D / 4) / 256, 256, 0, stream>>>(W, wb);
  gemm_kernel<<<dim3(NPAD / 128, D / 128), 256, 0, stream>>>(xb, wb, hb, rnorm, N, NPAD);

  int ngrp = (N + 31) / 32;
  gather_phase_kernel<<<8 * ngrp, 256, 0, stream>>>(hb, offsets, ecount, rnorm, csr, out, N, NPAD, 0);
  gather_phase_kernel<<<8 * ngrp, 256, 0, stream>>>(hb, offsets, ecount, rnorm, csr, out, N, NPAD, 8);
}

// Round 2
// 784.409 us; speedup vs baseline: 1.3157x; 1.3157x over previous
//
#include <hip/hip_runtime.h>
#include <hip/hip_bf16.h>
#include <stdint.h>

#define D 256
#define NBUCK 391            // ceil(100000 / 256) buckets of 256 nodes
#define BSHIFT 8
#define TILE 4096            // edges per block in binning pass

typedef short short8 __attribute__((ext_vector_type(8)));
typedef float f32x4 __attribute__((ext_vector_type(4)));
typedef float f32x2 __attribute__((ext_vector_type(2)));

__device__ __forceinline__ float bf2f(unsigned short u) {
  return __uint_as_float(((unsigned)u) << 16);
}
__device__ __forceinline__ unsigned short f2bf(float f) {
  unsigned u = __float_as_uint(f);
  unsigned r = u + 0x7FFFu + ((u >> 16) & 1u);
  return (unsigned short)(r >> 16);
}

// ---------------- K1: coarse bucket histogram (LDS-binned) ----------------
__global__ void bucket_hist_kernel(const int* __restrict__ src, int* __restrict__ bcount, int E) {
  __shared__ int h[NBUCK];
  for (int i = threadIdx.x; i < NBUCK; i += 256) h[i] = 0;
  __syncthreads();
  int gid = blockIdx.x * 256 + threadIdx.x;
  for (int e = gid; e < E; e += 256 * 256) atomicAdd(&h[src[e] >> BSHIFT], 1);
  __syncthreads();
  for (int i = threadIdx.x; i < NBUCK; i += 256) {
    int c = h[i];
    if (c) atomicAdd(&bcount[i], c);
  }
}

// ---------------- K2: exclusive scan of bucket counts ----------------
__global__ void bucket_scan_kernel(const int* __restrict__ bcount, int* __restrict__ bbase,
                                   int* __restrict__ gcursor) {
  __shared__ int sc[2][512];
  int tid = threadIdx.x;
  sc[0][tid] = (tid < NBUCK) ? bcount[tid] : 0;
  __syncthreads();
  int d = 0;
  for (int off = 1; off < 512; off <<= 1) {
    int v = sc[d][tid];
    if (tid >= off) v += sc[d][tid - off];
    sc[d ^ 1][tid] = v;
    __syncthreads();
    d ^= 1;
  }
  if (tid < NBUCK) {
    int excl = (tid == 0) ? 0 : sc[d][tid - 1];
    bbase[tid] = excl;
    gcursor[tid] = excl;
  }
}

// ---------------- K3: binning scatter ----------------
__launch_bounds__(256)
__global__ void binscatter_kernel(const int* __restrict__ src, const int* __restrict__ dst,
                                  int* __restrict__ gcursor, int* __restrict__ ebuf, int E) {
  __shared__ int hist[NBUCK];
  __shared__ int lstart[512];
  __shared__ int gbase[NBUCK];
  __shared__ int sc[2][512];
  __shared__ int stag[TILE];
  __shared__ unsigned short sbuck[TILE];

  int tid = threadIdx.x;
  int base = blockIdx.x * TILE;
  int tilecount = E - base;
  if (tilecount > TILE) tilecount = TILE;

  for (int i = tid; i < NBUCK; i += 256) hist[i] = 0;
  __syncthreads();

  int esrc[16], edst[16];
#pragma unroll
  for (int k = 0; k < 16; k++) {
    int e = base + k * 256 + tid;
    if (e < E) {
      esrc[k] = src[e];
      edst[k] = dst[e];
      atomicAdd(&hist[esrc[k] >> BSHIFT], 1);
    } else {
      esrc[k] = -1;
      edst[k] = 0;
    }
  }
  __syncthreads();

  for (int i = tid; i < 512; i += 256) sc[0][i] = (i < NBUCK) ? hist[i] : 0;
  __syncthreads();
  int d = 0;
  for (int off = 1; off < 512; off <<= 1) {
    for (int i = tid; i < 512; i += 256) {
      int v = sc[d][i];
      if (i >= off) v += sc[d][i - off];
      sc[d ^ 1][i] = v;
    }
    __syncthreads();
    d ^= 1;
  }
  for (int i = tid; i < 512; i += 256) lstart[i] = (i == 0) ? 0 : sc[d][i - 1];
  __syncthreads();

  for (int b = tid; b < NBUCK; b += 256) {
    int c = hist[b];
    if (c) gbase[b] = atomicAdd(&gcursor[b], c);
  }
  __syncthreads();

  for (int i = tid; i < NBUCK; i += 256) hist[i] = 0;
  __syncthreads();

#pragma unroll
  for (int k = 0; k < 16; k++) {
    if (esrc[k] >= 0) {
      int b = esrc[k] >> BSHIFT;
      int r = atomicAdd(&hist[b], 1);
      int pos = lstart[b] + r;
      stag[pos] = edst[k] | ((esrc[k] & 255) << 20);
      sbuck[pos] = (unsigned short)b;
    }
  }
  __syncthreads();

  for (int s = tid; s < tilecount; s += 256) {
    int b = sbuck[s];
    ebuf[gbase[b] + (s - lstart[b])] = stag[s];
  }
}

// ---------------- K4: per-bucket counting sort ----------------
__launch_bounds__(256)
__global__ void bucketsort_kernel(const int* __restrict__ ebuf, const int* __restrict__ bbase,
                                  const int* __restrict__ bcount, int* __restrict__ csr,
                                  int* __restrict__ offsets, int* __restrict__ ecount,
                                  float* __restrict__ rnorm, int N) {
  __shared__ int ncnt[256];
  __shared__ int nstart[256];
  __shared__ int sc[2][256];
  int tid = threadIdx.x;
  int b = blockIdx.x;
  int base = bbase[b];
  int cnt = bcount[b];
  int node0 = b << BSHIFT;

  ncnt[tid] = 0;
  __syncthreads();
  for (int s = tid; s < cnt; s += 256) {
    int v = ebuf[base + s];
    atomicAdd(&ncnt[v >> 20], 1);
  }
  __syncthreads();

  int mycnt = ncnt[tid];
  sc[0][tid] = mycnt;
  __syncthreads();
  int d = 0;
  for (int off = 1; off < 256; off <<= 1) {
    int v = sc[d][tid];
    if (tid >= off) v += sc[d][tid - off];
    sc[d ^ 1][tid] = v;
    __syncthreads();
    d ^= 1;
  }
  nstart[tid] = (tid == 0) ? 0 : sc[d][tid - 1];
  __syncthreads();

  int node = node0 + tid;
  if (node < N) {
    offsets[node] = base + nstart[tid];
    ecount[node] = mycnt;
    rnorm[node] = rsqrtf((float)(mycnt + 1));
  }

  ncnt[tid] = 0;
  __syncthreads();
  for (int s = tid; s < cnt; s += 256) {
    int v = ebuf[base + s];
    int nl = v >> 20;
    int r = atomicAdd(&ncnt[nl], 1);
    csr[base + nstart[nl] + r] = v & 0xFFFFF;
  }
}

// ---------------- fp32 -> bf16 conversions ----------------
__global__ void convx_kernel(const float* __restrict__ x, unsigned short* __restrict__ xb,
                             int n, int npad) {
  int i4 = blockIdx.x * 256 + threadIdx.x;
  long long elem = (long long)i4 * 4;
  if (elem >= (long long)npad * D) return;
  int row = (int)(elem / D);
  ushort4 o;
  if (row < n) {
    const float4 v = *(const float4*)&x[elem];
    o.x = f2bf(v.x); o.y = f2bf(v.y); o.z = f2bf(v.z); o.w = f2bf(v.w);
  } else {
    o = make_ushort4(0, 0, 0, 0);
  }
  *(ushort4*)&xb[elem] = o;
}

__global__ void convw_kernel(const float* __restrict__ w, unsigned short* __restrict__ wb) {
  int i4 = blockIdx.x * 256 + threadIdx.x;
  int elem = i4 * 4;
  const float4 v = *(const float4*)&w[elem];
  ushort4 o;
  o.x = f2bf(v.x); o.y = f2bf(v.y); o.z = f2bf(v.z); o.w = f2bf(v.w);
  *(ushort4*)&wb[elem] = o;
}

// ---------------- bf16 MFMA GEMM: hs = rsqrt(deg) * (x @ W^T) ----------------
// Output written in COLUMN-BLOCKED layout: hsb[cb][row][c] with cb = col>>4,
// c = col&15. One 16-col slice = npad*32 B = 3.2 MB -> fits a 4 MB per-XCD L2.
// Pad rows (gr >= n) are written with rn = 0 -> they are (+/-)0.0 in bf16;
// the gather uses row n as a zero-sentinel for invalid edge slots.
__launch_bounds__(256)
__global__ void gemm_kernel(const unsigned short* __restrict__ A,
                            const unsigned short* __restrict__ B,
                            unsigned short* __restrict__ Hout,
                            const float* __restrict__ rnorm, int n, int npad) {
  __shared__ unsigned short sA[128 * 32];
  __shared__ unsigned short sB[128 * 32];
  int tid = threadIdx.x;
  int wave = tid >> 6, lane = tid & 63;
  int wm = wave >> 1, wn = wave & 1;
  int l16 = lane & 15, quad = lane >> 4;
  int arow0 = blockIdx.x * 128;
  int brow0 = blockIdx.y * 128;

  f32x4 acc[4][4];
  const f32x4 zero = {0.f, 0.f, 0.f, 0.f};
#pragma unroll
  for (int i = 0; i < 4; i++)
#pragma unroll
    for (int j = 0; j < 4; j++) acc[i][j] = zero;

  for (int k0 = 0; k0 < 256; k0 += 32) {
#pragma unroll
    for (int it = 0; it < 2; ++it) {
      int c = it * 256 + tid;
      int row = c >> 2, cc = (c & 3) * 8;
      *(int4*)&sA[c * 8] = *(const int4*)&A[(arow0 + row) * 256 + k0 + cc];
      *(int4*)&sB[c * 8] = *(const int4*)&B[(brow0 + row) * 256 + k0 + cc];
    }
    __syncthreads();
    short8 af[4], bfr[4];
#pragma unroll
    for (int i = 0; i < 4; i++)
      af[i] = *(const short8*)&sA[(wm * 64 + i * 16 + l16) * 32 + quad * 8];
#pragma unroll
    for (int j = 0; j < 4; j++)
      bfr[j] = *(const short8*)&sB[(wn * 64 + j * 16 + l16) * 32 + quad * 8];
#pragma unroll
    for (int i = 0; i < 4; i++)
#pragma unroll
      for (int j = 0; j < 4; j++)
        acc[i][j] = __builtin_amdgcn_mfma_f32_16x16x32_bf16(af[i], bfr[j], acc[i][j], 0, 0, 0);
    __syncthreads();
  }

  int cbbase = (brow0 >> 4) + wn * 4;
#pragma unroll
  for (int i = 0; i < 4; i++) {
    int rowb = arow0 + wm * 64 + i * 16 + quad * 4;
#pragma unroll
    for (int r = 0; r < 4; r++) {
      int gr = rowb + r;
      float rn = (gr < n) ? rnorm[gr] : 0.f;
#pragma unroll
      for (int j = 0; j < 4; j++) {
        Hout[((size_t)(cbbase + j) * npad + gr) * 16 + l16] = f2bf(acc[i][j][r] * rn);
      }
    }
  }
}

// ---------------- phased CSR gather: one 16-col slice per XCD ----------------
// Lane layout: ni = lane>>3 (node slot 0..7), c = lane&7 (col-pair slot).
// Lane (ni,c) accumulates node ni's col-pair c directly -> no cross-lane
// reduce, no per-node serial loop. Edge indices are staged 8-per-node in a
// register chunk (one NT load), distributed per step by __shfl broadcast,
// with the next chunk prefetched during compute. Invalid slots redirect to
// slice row n (all zeros, written by gemm's rn=0 pad path) -> no per-step
// masking. Block->XCD pinning: phase = bid&7 (confirmed by FETCH drop r1).
__launch_bounds__(256)
__global__ void gather_phase_kernel(const unsigned short* __restrict__ hsb,
                                    const int* __restrict__ offsets,
                                    const int* __restrict__ ecount,
                                    const float* __restrict__ rnorm,
                                    const int* __restrict__ csr,
                                    float* __restrict__ out,
                                    int n, int npad, int ngrp, int E) {
  const int lane = threadIdx.x & 63;
  const int wave = threadIdx.x >> 6;
  int bid = blockIdx.x;
  int pbase = 0;
  if (bid >= 8 * ngrp) { pbase = 8; bid -= 8 * ngrp; }
  const int cb = pbase + (bid & 7);
  const int grp = bid >> 3;
  const int ni = lane >> 3;   // node slot
  const int c = lane & 7;     // col-pair slot (also csr chunk slot)
  const int sl = lane & 56;   // base lane of my node slot
  const unsigned short* slicec = hsb + (size_t)cb * npad * 16 + c * 2;

  int node = grp * 32 + wave * 8 + ni;
  int nid = (node < n) ? node : (n - 1);
  int start = __builtin_nontemporal_load(&offsets[nid]);
  int cnt = __builtin_nontemporal_load(&ecount[nid]);

  // wave-uniform max count across the 8 node slots
  int cmax = cnt;
  cmax = max(cmax, __shfl_xor(cmax, 8));
  cmax = max(cmax, __shfl_xor(cmax, 16));
  cmax = max(cmax, __shfl_xor(cmax, 32));

  float a0 = 0.f, a1 = 0.f;
  // csr allocated with 64 pad entries; prefetch addrs clamped to E (in pad).
  int rcur = __builtin_nontemporal_load(&csr[min(start + c, E)]);
  for (int T = 0; T < cmax; T += 8) {
    int rnext = __builtin_nontemporal_load(&csr[min(start + T + 8 + c, E)]);
    int rm = (T + c < cnt) ? rcur : n;   // invalid slot -> zero row n
#pragma unroll
    for (int t = 0; t < 8; ++t) {
      int d0 = __shfl(rm, sl + t);
      unsigned u = *(const unsigned*)&slicec[(size_t)d0 * 16];
      a0 += bf2f((unsigned short)u);
      a1 += bf2f((unsigned short)(u >> 16));
    }
    rcur = rnext;
  }

  unsigned us = *(const unsigned*)&slicec[(size_t)nid * 16];
  float rn = __builtin_nontemporal_load(&rnorm[nid]);
  f32x2 o;
  o.x = rn * (a0 + bf2f((unsigned short)us));
  o.y = rn * (a1 + bf2f((unsigned short)(us >> 16)));
  if (node < n)
    __builtin_nontemporal_store(o, (f32x2*)&out[(size_t)node * 256 + cb * 16 + c * 2]);
}

extern "C" void kernel_launch(void* const* d_in, const int* in_sizes, int n_in,
                              void* d_out, int out_size, void* d_ws, size_t ws_size,
                              hipStream_t stream) {
  const float* x = (const float*)d_in[0];
  const float* W = (const float*)d_in[1];
  const int* ei = (const int*)d_in[2];
  float* out = (float*)d_out;

  int N = in_sizes[0] / D;        // 100000
  int E = in_sizes[2] / 2;        // 3200000
  int NPAD = (N + 127) & ~127;
  const int* src = ei;
  const int* dst = ei + E;

  char* p = (char*)d_ws;
  auto alloc = [&](size_t b) {
    char* r = p;
    p += (b + 255) & ~(size_t)255;
    return r;
  };
  unsigned short* xb = (unsigned short*)alloc((size_t)NPAD * D * 2);
  unsigned short* wb = (unsigned short*)alloc((size_t)D * D * 2);
  unsigned short* hb = (unsigned short*)alloc((size_t)NPAD * D * 2);
  int* csr = (int*)alloc((size_t)(E + 64) * 4);   // +64 pad for clamped prefetch
  int* offsets = (int*)alloc((size_t)N * 4);
  int* ecount = (int*)alloc((size_t)N * 4);
  float* rnorm = (float*)alloc((size_t)N * 4);
  int* bcount = (int*)alloc(NBUCK * 4);
  int* bbase = (int*)alloc(NBUCK * 4);
  int* gcursor = (int*)alloc(NBUCK * 4);
  // ebuf (E*4 = 12.8 MB) aliases hb (51 MB): dead before gemm writes hb
  int* ebuf = (int*)hb;

  hipMemsetAsync(bcount, 0, NBUCK * 4, stream);
  bucket_hist_kernel<<<256, 256, 0, stream>>>(src, bcount, E);
  bucket_scan_kernel<<<1, 512, 0, stream>>>(bcount, bbase, gcursor);
  binscatter_kernel<<<(E + TILE - 1) / TILE, 256, 0, stream>>>(src, dst, gcursor, ebuf, E);
  bucketsort_kernel<<<NBUCK, 256, 0, stream>>>(ebuf, bbase, bcount, csr, offsets, ecount, rnorm, N);
  convx_kernel<<<(NPAD * (D / 4) + 255) / 256, 256, 0, stream>>>(x, xb, N, NPAD);
  convw_kernel<<<(D * D / 4) / 256, 256, 0, stream>>>(W, wb);
  gemm_kernel<<<dim3(NPAD / 128, D / 128), 256, 0, stream>>>(xb, wb, hb, rnorm, N, NPAD);

  int ngrp = (N + 31) / 32;   // 3125 (N divisible by 32)
  gather_phase_kernel<<<16 * ngrp, 256, 0, stream>>>(hb, offsets, ecount, rnorm, csr, out,
                                                     N, NPAD, ngrp, E);
}

// Round 3
// 661.724 us; speedup vs baseline: 1.5596x; 1.1854x over previous
//
#include <hip/hip_runtime.h>
#include <hip/hip_bf16.h>
#include <stdint.h>

#define D 256
#define NBUCK 391            // ceil(100000 / 256) buckets of 256 nodes
#define BSHIFT 8
#define TILE 4096            // edges per block in binning pass

typedef short short8 __attribute__((ext_vector_type(8)));
typedef float f32x4 __attribute__((ext_vector_type(4)));
typedef float f32x2 __attribute__((ext_vector_type(2)));
typedef unsigned int u32x2 __attribute__((ext_vector_type(2)));

__device__ __forceinline__ float bf2f(unsigned short u) {
  return __uint_as_float(((unsigned)u) << 16);
}
__device__ __forceinline__ unsigned short f2bf(float f) {
  unsigned u = __float_as_uint(f);
  unsigned r = u + 0x7FFFu + ((u >> 16) & 1u);
  return (unsigned short)(r >> 16);
}

// ---------------- K1: coarse bucket histogram (LDS-binned) ----------------
__global__ void bucket_hist_kernel(const int* __restrict__ src, int* __restrict__ bcount, int E) {
  __shared__ int h[NBUCK];
  for (int i = threadIdx.x; i < NBUCK; i += 256) h[i] = 0;
  __syncthreads();
  int gid = blockIdx.x * 256 + threadIdx.x;
  for (int e = gid; e < E; e += 256 * 256) atomicAdd(&h[src[e] >> BSHIFT], 1);
  __syncthreads();
  for (int i = threadIdx.x; i < NBUCK; i += 256) {
    int c = h[i];
    if (c) atomicAdd(&bcount[i], c);
  }
}

// ---------------- K2: exclusive scan of bucket counts ----------------
__global__ void bucket_scan_kernel(const int* __restrict__ bcount, int* __restrict__ bbase,
                                   int* __restrict__ gcursor) {
  __shared__ int sc[2][512];
  int tid = threadIdx.x;
  sc[0][tid] = (tid < NBUCK) ? bcount[tid] : 0;
  __syncthreads();
  int d = 0;
  for (int off = 1; off < 512; off <<= 1) {
    int v = sc[d][tid];
    if (tid >= off) v += sc[d][tid - off];
    sc[d ^ 1][tid] = v;
    __syncthreads();
    d ^= 1;
  }
  if (tid < NBUCK) {
    int excl = (tid == 0) ? 0 : sc[d][tid - 1];
    bbase[tid] = excl;
    gcursor[tid] = excl;
  }
}

// ---------------- K3: binning scatter ----------------
__launch_bounds__(256)
__global__ void binscatter_kernel(const int* __restrict__ src, const int* __restrict__ dst,
                                  int* __restrict__ gcursor, int* __restrict__ ebuf, int E) {
  __shared__ int hist[NBUCK];
  __shared__ int lstart[512];
  __shared__ int gbase[NBUCK];
  __shared__ int sc[2][512];
  __shared__ int stag[TILE];
  __shared__ unsigned short sbuck[TILE];

  int tid = threadIdx.x;
  int base = blockIdx.x * TILE;
  int tilecount = E - base;
  if (tilecount > TILE) tilecount = TILE;

  for (int i = tid; i < NBUCK; i += 256) hist[i] = 0;
  __syncthreads();

  int esrc[16], edst[16];
#pragma unroll
  for (int k = 0; k < 16; k++) {
    int e = base + k * 256 + tid;
    if (e < E) {
      esrc[k] = src[e];
      edst[k] = dst[e];
      atomicAdd(&hist[esrc[k] >> BSHIFT], 1);
    } else {
      esrc[k] = -1;
      edst[k] = 0;
    }
  }
  __syncthreads();

  for (int i = tid; i < 512; i += 256) sc[0][i] = (i < NBUCK) ? hist[i] : 0;
  __syncthreads();
  int d = 0;
  for (int off = 1; off < 512; off <<= 1) {
    for (int i = tid; i < 512; i += 256) {
      int v = sc[d][i];
      if (i >= off) v += sc[d][i - off];
      sc[d ^ 1][i] = v;
    }
    __syncthreads();
    d ^= 1;
  }
  for (int i = tid; i < 512; i += 256) lstart[i] = (i == 0) ? 0 : sc[d][i - 1];
  __syncthreads();

  for (int b = tid; b < NBUCK; b += 256) {
    int c = hist[b];
    if (c) gbase[b] = atomicAdd(&gcursor[b], c);
  }
  __syncthreads();

  for (int i = tid; i < NBUCK; i += 256) hist[i] = 0;
  __syncthreads();

#pragma unroll
  for (int k = 0; k < 16; k++) {
    if (esrc[k] >= 0) {
      int b = esrc[k] >> BSHIFT;
      int r = atomicAdd(&hist[b], 1);
      int pos = lstart[b] + r;
      stag[pos] = edst[k] | ((esrc[k] & 255) << 20);
      sbuck[pos] = (unsigned short)b;
    }
  }
  __syncthreads();

  for (int s = tid; s < tilecount; s += 256) {
    int b = sbuck[s];
    ebuf[gbase[b] + (s - lstart[b])] = stag[s];
  }
}

// ---------------- K4: per-bucket counting sort, split by dst-range ----------------
// Key = node-local (8b) * 2 + (dst >= half). Per node the csr list is
// [range-0 dsts][range-1 dsts]; meta0 = {off0, cnt0}, meta1 = {off1, cnt1}.
__launch_bounds__(256)
__global__ void bucketsort_kernel(const int* __restrict__ ebuf, const int* __restrict__ bbase,
                                  const int* __restrict__ bcount, int* __restrict__ csr,
                                  int2* __restrict__ meta0, int2* __restrict__ meta1,
                                  float* __restrict__ rnorm, int N, int half) {
  __shared__ int ncnt[512];
  __shared__ int nstart[512];
  __shared__ int sc[2][512];
  int tid = threadIdx.x;
  int b = blockIdx.x;
  int base = bbase[b];
  int cnt = bcount[b];
  int node0 = b << BSHIFT;

  for (int i = tid; i < 512; i += 256) ncnt[i] = 0;
  __syncthreads();
  for (int s = tid; s < cnt; s += 256) {
    int v = ebuf[base + s];
    int key = ((v >> 20) << 1) | (((v & 0xFFFFF) >= half) ? 1 : 0);
    atomicAdd(&ncnt[key], 1);
  }
  __syncthreads();

  for (int i = tid; i < 512; i += 256) sc[0][i] = ncnt[i];
  __syncthreads();
  int d = 0;
  for (int off = 1; off < 512; off <<= 1) {
    for (int i = tid; i < 512; i += 256) {
      int v = sc[d][i];
      if (i >= off) v += sc[d][i - off];
      sc[d ^ 1][i] = v;
    }
    __syncthreads();
    d ^= 1;
  }
  for (int i = tid; i < 512; i += 256) nstart[i] = (i == 0) ? 0 : sc[d][i - 1];
  __syncthreads();

  int node = node0 + tid;
  if (node < N) {
    int c0 = ncnt[tid * 2], c1 = ncnt[tid * 2 + 1];
    int off0 = base + nstart[tid * 2];
    meta0[node] = make_int2(off0, c0);
    meta1[node] = make_int2(off0 + c0, c1);
    rnorm[node] = rsqrtf((float)(c0 + c1 + 1));
  }

  for (int i = tid; i < 512; i += 256) ncnt[i] = 0;
  __syncthreads();
  for (int s = tid; s < cnt; s += 256) {
    int v = ebuf[base + s];
    int dstv = v & 0xFFFFF;
    int key = ((v >> 20) << 1) | ((dstv >= half) ? 1 : 0);
    int r = atomicAdd(&ncnt[key], 1);
    csr[base + nstart[key] + r] = dstv;
  }
}

// ---------------- fp32 -> bf16 conversions ----------------
__global__ void convx_kernel(const float* __restrict__ x, unsigned short* __restrict__ xb,
                             int n, int npad) {
  int i4 = blockIdx.x * 256 + threadIdx.x;
  long long elem = (long long)i4 * 4;
  if (elem >= (long long)npad * D) return;
  int row = (int)(elem / D);
  ushort4 o;
  if (row < n) {
    const float4 v = *(const float4*)&x[elem];
    o.x = f2bf(v.x); o.y = f2bf(v.y); o.z = f2bf(v.z); o.w = f2bf(v.w);
  } else {
    o = make_ushort4(0, 0, 0, 0);
  }
  *(ushort4*)&xb[elem] = o;
}

__global__ void convw_kernel(const float* __restrict__ w, unsigned short* __restrict__ wb) {
  int i4 = blockIdx.x * 256 + threadIdx.x;
  int elem = i4 * 4;
  const float4 v = *(const float4*)&w[elem];
  ushort4 o;
  o.x = f2bf(v.x); o.y = f2bf(v.y); o.z = f2bf(v.z); o.w = f2bf(v.w);
  *(ushort4*)&wb[elem] = o;
}

// ---------------- bf16 MFMA GEMM: hs = rsqrt(deg) * (x @ W^T) ----------------
// Output in 32-COL-BLOCKED layout: hsb[cb][row][c] with cb = col>>5, c = col&31.
// One 32-col slice over a dst-half = (npad/2)*64 B = 3.2 MB -> L2-resident.
// Pad rows (gr >= n) written with rn = 0 -> zeros; gather uses row n as the
// zero-sentinel for invalid edge slots.
__launch_bounds__(256)
__global__ void gemm_kernel(const unsigned short* __restrict__ A,
                            const unsigned short* __restrict__ B,
                            unsigned short* __restrict__ Hout,
                            const float* __restrict__ rnorm, int n, int npad) {
  __shared__ unsigned short sA[128 * 32];
  __shared__ unsigned short sB[128 * 32];
  int tid = threadIdx.x;
  int wave = tid >> 6, lane = tid & 63;
  int wm = wave >> 1, wn = wave & 1;
  int l16 = lane & 15, quad = lane >> 4;
  int arow0 = blockIdx.x * 128;
  int brow0 = blockIdx.y * 128;

  f32x4 acc[4][4];
  const f32x4 zero = {0.f, 0.f, 0.f, 0.f};
#pragma unroll
  for (int i = 0; i < 4; i++)
#pragma unroll
    for (int j = 0; j < 4; j++) acc[i][j] = zero;

  for (int k0 = 0; k0 < 256; k0 += 32) {
#pragma unroll
    for (int it = 0; it < 2; ++it) {
      int c = it * 256 + tid;
      int row = c >> 2, cc = (c & 3) * 8;
      *(int4*)&sA[c * 8] = *(const int4*)&A[(arow0 + row) * 256 + k0 + cc];
      *(int4*)&sB[c * 8] = *(const int4*)&B[(brow0 + row) * 256 + k0 + cc];
    }
    __syncthreads();
    short8 af[4], bfr[4];
#pragma unroll
    for (int i = 0; i < 4; i++)
      af[i] = *(const short8*)&sA[(wm * 64 + i * 16 + l16) * 32 + quad * 8];
#pragma unroll
    for (int j = 0; j < 4; j++)
      bfr[j] = *(const short8*)&sB[(wn * 64 + j * 16 + l16) * 32 + quad * 8];
#pragma unroll
    for (int i = 0; i < 4; i++)
#pragma unroll
      for (int j = 0; j < 4; j++)
        acc[i][j] = __builtin_amdgcn_mfma_f32_16x16x32_bf16(af[i], bfr[j], acc[i][j], 0, 0, 0);
    __syncthreads();
  }

  // col = brow0 + wn*64 + j*16 + l16 -> cb = col>>5, c32 = (j&1)*16 + l16
  int cbb = (brow0 >> 5) + wn * 2;
#pragma unroll
  for (int i = 0; i < 4; i++) {
    int rowb = arow0 + wm * 64 + i * 16 + quad * 4;
#pragma unroll
    for (int r = 0; r < 4; r++) {
      int gr = rowb + r;
      float rn = (gr < n) ? rnorm[gr] : 0.f;
#pragma unroll
      for (int j = 0; j < 4; j++) {
        Hout[((size_t)(cbb + (j >> 1)) * npad + gr) * 32 + (j & 1) * 16 + l16] =
            f2bf(acc[i][j][r] * rn);
      }
    }
  }
}

// ---------------- two-pass CSR gather: 32-col slice per XCD, dst-range split --
// cb = bid&7 -> one 32-col slice per XCD for the whole launch. Each pass only
// touches dst rows of one half (csr is range-sorted), so the random-read set
// per XCD is 3.2 MB -> L2-resident. Pass 0: self + range-0 edges, write raw
// f32 partials. Pass 1: + range-1 edges, apply rnorm, final write.
// Lane layout: ni = lane>>3 (node slot), c = lane&7 (owns 4 cols = 8 B).
// Per step one dwordx2 wave-load = 8 fully-used 64 B lines (8 edge-visits).
__launch_bounds__(256)
__global__ void gather_pass_kernel(const unsigned short* __restrict__ hsb,
                                   const int2* __restrict__ meta,
                                   const float* __restrict__ rnorm,
                                   const int* __restrict__ csr,
                                   float* __restrict__ out,
                                   int n, int npad, int E, int PASS) {
  const int lane = threadIdx.x & 63;
  const int wave = threadIdx.x >> 6;
  const int bid = blockIdx.x;
  const int cb = bid & 7;       // slice == XCD (round-robin dispatch heuristic)
  const int grp = bid >> 3;
  const int ni = lane >> 3;     // node slot 0..7
  const int c = lane & 7;       // 4-col group within the 32-col slice
  const int sl = lane & 56;
  const unsigned short* slicec = hsb + (size_t)cb * npad * 32 + c * 4;

  int node = grp * 32 + wave * 8 + ni;
  int nid = (node < n) ? node : (n - 1);
  long long mm = __builtin_nontemporal_load((const long long*)&meta[nid]);
  int start = (int)mm;
  int cnt = (int)(mm >> 32);

  // wave-uniform max count across the 8 node slots
  int cmax = cnt;
  cmax = max(cmax, __shfl_xor(cmax, 8));
  cmax = max(cmax, __shfl_xor(cmax, 16));
  cmax = max(cmax, __shfl_xor(cmax, 32));

  float a0 = 0.f, a1 = 0.f, a2 = 0.f, a3 = 0.f;
  // csr has 64 pad entries; prefetch addrs clamped into the pad region.
  int rcur = __builtin_nontemporal_load(&csr[min(start + c, E)]);
  for (int T = 0; T < cmax; T += 8) {
    int rnext = __builtin_nontemporal_load(&csr[min(start + T + 8 + c, E)]);
    int rm = (T + c < cnt) ? rcur : n;   // invalid slot -> zero row n
#pragma unroll
    for (int t = 0; t < 8; ++t) {
      int d0 = __shfl(rm, sl + t);
      u32x2 u = *(const u32x2*)&slicec[(size_t)d0 * 32];
      a0 += bf2f((unsigned short)u[0]);
      a1 += bf2f((unsigned short)(u[0] >> 16));
      a2 += bf2f((unsigned short)u[1]);
      a3 += bf2f((unsigned short)(u[1] >> 16));
    }
    rcur = rnext;
  }

  float* op = &out[(size_t)nid * 256 + cb * 32 + c * 4];
  if (PASS == 0) {
    // self term (row nid of own slice), raw partial write
    u32x2 us = *(const u32x2*)&slicec[(size_t)nid * 32];
    f32x4 o;
    o[0] = a0 + bf2f((unsigned short)us[0]);
    o[1] = a1 + bf2f((unsigned short)(us[0] >> 16));
    o[2] = a2 + bf2f((unsigned short)us[1]);
    o[3] = a3 + bf2f((unsigned short)(us[1] >> 16));
    if (node < n) __builtin_nontemporal_store(o, (f32x4*)op);
  } else {
    float rn = __builtin_nontemporal_load(&rnorm[nid]);
    f32x4 prev = __builtin_nontemporal_load((const f32x4*)op);
    f32x4 o;
    o[0] = rn * (prev[0] + a0);
    o[1] = rn * (prev[1] + a1);
    o[2] = rn * (prev[2] + a2);
    o[3] = rn * (prev[3] + a3);
    if (node < n) __builtin_nontemporal_store(o, (f32x4*)op);
  }
}

extern "C" void kernel_launch(void* const* d_in, const int* in_sizes, int n_in,
                              void* d_out, int out_size, void* d_ws, size_t ws_size,
                              hipStream_t stream) {
  const float* x = (const float*)d_in[0];
  const float* W = (const float*)d_in[1];
  const int* ei = (const int*)d_in[2];
  float* out = (float*)d_out;

  int N = in_sizes[0] / D;        // 100000
  int E = in_sizes[2] / 2;        // 3200000
  int NPAD = (N + 127) & ~127;
  int HALF = N >> 1;              // dst-range split point
  const int* src = ei;
  const int* dst = ei + E;

  char* p = (char*)d_ws;
  auto alloc = [&](size_t b) {
    char* r = p;
    p += (b + 255) & ~(size_t)255;
    return r;
  };
  unsigned short* xb = (unsigned short*)alloc((size_t)NPAD * D * 2);
  unsigned short* wb = (unsigned short*)alloc((size_t)D * D * 2);
  unsigned short* hb = (unsigned short*)alloc((size_t)NPAD * D * 2);
  int* csr = (int*)alloc((size_t)(E + 64) * 4);   // +64 pad for clamped prefetch
  int2* meta0 = (int2*)alloc((size_t)N * 8);
  int2* meta1 = (int2*)alloc((size_t)N * 8);
  float* rnorm = (float*)alloc((size_t)N * 4);
  int* bcount = (int*)alloc(NBUCK * 4);
  int* bbase = (int*)alloc(NBUCK * 4);
  int* gcursor = (int*)alloc(NBUCK * 4);
  // ebuf (E*4 = 12.8 MB) aliases hb (51 MB): dead before gemm writes hb
  int* ebuf = (int*)hb;

  hipMemsetAsync(bcount, 0, NBUCK * 4, stream);
  bucket_hist_kernel<<<256, 256, 0, stream>>>(src, bcount, E);
  bucket_scan_kernel<<<1, 512, 0, stream>>>(bcount, bbase, gcursor);
  binscatter_kernel<<<(E + TILE - 1) / TILE, 256, 0, stream>>>(src, dst, gcursor, ebuf, E);
  bucketsort_kernel<<<NBUCK, 256, 0, stream>>>(ebuf, bbase, bcount, csr, meta0, meta1,
                                               rnorm, N, HALF);
  convx_kernel<<<(NPAD * (D / 4) + 255) / 256, 256, 0, stream>>>(x, xb, N, NPAD);
  convw_kernel<<<(D * D / 4) / 256, 256, 0, stream>>>(W, wb);
  gemm_kernel<<<dim3(NPAD / 128, D / 128), 256, 0, stream>>>(xb, wb, hb, rnorm, N, NPAD);

  int ngrp = (N + 31) / 32;       // 3125
  gather_pass_kernel<<<8 * ngrp, 256, 0, stream>>>(hb, meta0, rnorm, csr, out, N, NPAD, E, 0);
  gather_pass_kernel<<<8 * ngrp, 256, 0, stream>>>(hb, meta1, rnorm, csr, out, N, NPAD, E, 1);
}

// Round 4
// 548.163 us; speedup vs baseline: 1.8827x; 1.2072x over previous
//
#include <hip/hip_runtime.h>
#include <hip/hip_bf16.h>
#include <stdint.h>

#define D 256
#define NBUCK 391            // ceil(100000 / 256) buckets of 256 nodes
#define BSHIFT 8
#define TILE 4096            // edges per block in binning pass

typedef short short8 __attribute__((ext_vector_type(8)));
typedef float f32x4 __attribute__((ext_vector_type(4)));
typedef unsigned int u32x2 __attribute__((ext_vector_type(2)));

__device__ __forceinline__ float bf2f(unsigned short u) {
  return __uint_as_float(((unsigned)u) << 16);
}
__device__ __forceinline__ unsigned short f2bf(float f) {
  unsigned u = __float_as_uint(f);
  unsigned r = u + 0x7FFFu + ((u >> 16) & 1u);
  return (unsigned short)(r >> 16);
}

// ---------------- K1: coarse bucket histogram (LDS-binned) ----------------
__global__ void bucket_hist_kernel(const int* __restrict__ src, int* __restrict__ bcount, int E) {
  __shared__ int h[NBUCK];
  for (int i = threadIdx.x; i < NBUCK; i += 256) h[i] = 0;
  __syncthreads();
  int gid = blockIdx.x * 256 + threadIdx.x;
  for (int e = gid; e < E; e += 256 * 256) atomicAdd(&h[src[e] >> BSHIFT], 1);
  __syncthreads();
  for (int i = threadIdx.x; i < NBUCK; i += 256) {
    int c = h[i];
    if (c) atomicAdd(&bcount[i], c);
  }
}

// ---------------- K2: exclusive scan of bucket counts ----------------
__global__ void bucket_scan_kernel(const int* __restrict__ bcount, int* __restrict__ bbase,
                                   int* __restrict__ gcursor) {
  __shared__ int sc[2][512];
  int tid = threadIdx.x;
  sc[0][tid] = (tid < NBUCK) ? bcount[tid] : 0;
  __syncthreads();
  int d = 0;
  for (int off = 1; off < 512; off <<= 1) {
    int v = sc[d][tid];
    if (tid >= off) v += sc[d][tid - off];
    sc[d ^ 1][tid] = v;
    __syncthreads();
    d ^= 1;
  }
  if (tid < NBUCK) {
    int excl = (tid == 0) ? 0 : sc[d][tid - 1];
    bbase[tid] = excl;
    gcursor[tid] = excl;
  }
}

// ---------------- K3: binning scatter ----------------
__launch_bounds__(256)
__global__ void binscatter_kernel(const int* __restrict__ src, const int* __restrict__ dst,
                                  int* __restrict__ gcursor, int* __restrict__ ebuf, int E) {
  __shared__ int hist[NBUCK];
  __shared__ int lstart[512];
  __shared__ int gbase[NBUCK];
  __shared__ int sc[2][512];
  __shared__ int stag[TILE];
  __shared__ unsigned short sbuck[TILE];

  int tid = threadIdx.x;
  int base = blockIdx.x * TILE;
  int tilecount = E - base;
  if (tilecount > TILE) tilecount = TILE;

  for (int i = tid; i < NBUCK; i += 256) hist[i] = 0;
  __syncthreads();

  int esrc[16], edst[16];
#pragma unroll
  for (int k = 0; k < 16; k++) {
    int e = base + k * 256 + tid;
    if (e < E) {
      esrc[k] = src[e];
      edst[k] = dst[e];
      atomicAdd(&hist[esrc[k] >> BSHIFT], 1);
    } else {
      esrc[k] = -1;
      edst[k] = 0;
    }
  }
  __syncthreads();

  for (int i = tid; i < 512; i += 256) sc[0][i] = (i < NBUCK) ? hist[i] : 0;
  __syncthreads();
  int d = 0;
  for (int off = 1; off < 512; off <<= 1) {
    for (int i = tid; i < 512; i += 256) {
      int v = sc[d][i];
      if (i >= off) v += sc[d][i - off];
      sc[d ^ 1][i] = v;
    }
    __syncthreads();
    d ^= 1;
  }
  for (int i = tid; i < 512; i += 256) lstart[i] = (i == 0) ? 0 : sc[d][i - 1];
  __syncthreads();

  for (int b = tid; b < NBUCK; b += 256) {
    int c = hist[b];
    if (c) gbase[b] = atomicAdd(&gcursor[b], c);
  }
  __syncthreads();

  for (int i = tid; i < NBUCK; i += 256) hist[i] = 0;
  __syncthreads();

#pragma unroll
  for (int k = 0; k < 16; k++) {
    if (esrc[k] >= 0) {
      int b = esrc[k] >> BSHIFT;
      int r = atomicAdd(&hist[b], 1);
      int pos = lstart[b] + r;
      stag[pos] = edst[k] | ((esrc[k] & 255) << 20);
      sbuck[pos] = (unsigned short)b;
    }
  }
  __syncthreads();

  for (int s = tid; s < tilecount; s += 256) {
    int b = sbuck[s];
    ebuf[gbase[b] + (s - lstart[b])] = stag[s];
  }
}

// ---------------- K4: per-bucket counting sort ----------------
__launch_bounds__(256)
__global__ void bucketsort_kernel(const int* __restrict__ ebuf, const int* __restrict__ bbase,
                                  const int* __restrict__ bcount, int* __restrict__ csr,
                                  int2* __restrict__ meta, float* __restrict__ rnorm, int N) {
  __shared__ int ncnt[256];
  __shared__ int nstart[256];
  __shared__ int sc[2][256];
  int tid = threadIdx.x;
  int b = blockIdx.x;
  int base = bbase[b];
  int cnt = bcount[b];
  int node0 = b << BSHIFT;

  ncnt[tid] = 0;
  __syncthreads();
  for (int s = tid; s < cnt; s += 256) {
    int v = ebuf[base + s];
    atomicAdd(&ncnt[v >> 20], 1);
  }
  __syncthreads();

  int mycnt = ncnt[tid];
  sc[0][tid] = mycnt;
  __syncthreads();
  int d = 0;
  for (int off = 1; off < 256; off <<= 1) {
    int v = sc[d][tid];
    if (tid >= off) v += sc[d][tid - off];
    sc[d ^ 1][tid] = v;
    __syncthreads();
    d ^= 1;
  }
  nstart[tid] = (tid == 0) ? 0 : sc[d][tid - 1];
  __syncthreads();

  int node = node0 + tid;
  if (node < N) {
    meta[node] = make_int2(base + nstart[tid], mycnt);
    rnorm[node] = rsqrtf((float)(mycnt + 1));
  }

  ncnt[tid] = 0;
  __syncthreads();
  for (int s = tid; s < cnt; s += 256) {
    int v = ebuf[base + s];
    int nl = v >> 20;
    int r = atomicAdd(&ncnt[nl], 1);
    csr[base + nstart[nl] + r] = v & 0xFFFFF;
  }
}

// ---------------- fp32 -> bf16 conversions ----------------
__global__ void convx_kernel(const float* __restrict__ x, unsigned short* __restrict__ xb,
                             int n, int npad) {
  int i4 = blockIdx.x * 256 + threadIdx.x;
  long long elem = (long long)i4 * 4;
  if (elem >= (long long)npad * D) return;
  int row = (int)(elem / D);
  ushort4 o;
  if (row < n) {
    const float4 v = *(const float4*)&x[elem];
    o.x = f2bf(v.x); o.y = f2bf(v.y); o.z = f2bf(v.z); o.w = f2bf(v.w);
  } else {
    o = make_ushort4(0, 0, 0, 0);
  }
  *(ushort4*)&xb[elem] = o;
}

__global__ void convw_kernel(const float* __restrict__ w, unsigned short* __restrict__ wb) {
  int i4 = blockIdx.x * 256 + threadIdx.x;
  int elem = i4 * 4;
  const float4 v = *(const float4*)&w[elem];
  ushort4 o;
  o.x = f2bf(v.x); o.y = f2bf(v.y); o.z = f2bf(v.z); o.w = f2bf(v.w);
  *(ushort4*)&wb[elem] = o;
}

// ---------------- bf16 MFMA GEMM: hs = rsqrt(deg) * (x @ W^T) ----------------
// Row-major output [npad][256]; pad rows (gr >= n) written with rn = 0.
__launch_bounds__(256)
__global__ void gemm_kernel(const unsigned short* __restrict__ A,
                            const unsigned short* __restrict__ B,
                            unsigned short* __restrict__ Hout,
                            const float* __restrict__ rnorm, int n) {
  __shared__ unsigned short sA[128 * 32];
  __shared__ unsigned short sB[128 * 32];
  int tid = threadIdx.x;
  int wave = tid >> 6, lane = tid & 63;
  int wm = wave >> 1, wn = wave & 1;
  int l16 = lane & 15, quad = lane >> 4;
  int arow0 = blockIdx.x * 128;
  int brow0 = blockIdx.y * 128;

  f32x4 acc[4][4];
  const f32x4 zero = {0.f, 0.f, 0.f, 0.f};
#pragma unroll
  for (int i = 0; i < 4; i++)
#pragma unroll
    for (int j = 0; j < 4; j++) acc[i][j] = zero;

  for (int k0 = 0; k0 < 256; k0 += 32) {
#pragma unroll
    for (int it = 0; it < 2; ++it) {
      int c = it * 256 + tid;
      int row = c >> 2, cc = (c & 3) * 8;
      *(int4*)&sA[c * 8] = *(const int4*)&A[(arow0 + row) * 256 + k0 + cc];
      *(int4*)&sB[c * 8] = *(const int4*)&B[(brow0 + row) * 256 + k0 + cc];
    }
    __syncthreads();
    short8 af[4], bfr[4];
#pragma unroll
    for (int i = 0; i < 4; i++)
      af[i] = *(const short8*)&sA[(wm * 64 + i * 16 + l16) * 32 + quad * 8];
#pragma unroll
    for (int j = 0; j < 4; j++)
      bfr[j] = *(const short8*)&sB[(wn * 64 + j * 16 + l16) * 32 + quad * 8];
#pragma unroll
    for (int i = 0; i < 4; i++)
#pragma unroll
      for (int j = 0; j < 4; j++)
        acc[i][j] = __builtin_amdgcn_mfma_f32_16x16x32_bf16(af[i], bfr[j], acc[i][j], 0, 0, 0);
    __syncthreads();
  }

#pragma unroll
  for (int i = 0; i < 4; i++) {
    int rowb = arow0 + wm * 64 + i * 16 + quad * 4;
#pragma unroll
    for (int r = 0; r < 4; r++) {
      int gr = rowb + r;
      float rn = (gr < n) ? rnorm[gr] : 0.f;
#pragma unroll
      for (int j = 0; j < 4; j++) {
        int col = brow0 + wn * 64 + j * 16 + l16;
        Hout[(size_t)gr * 256 + col] = f2bf(acc[i][j][r] * rn);
      }
    }
  }
}

// ---------------- full-row CSR gather: 1 wave-load = 1 edge = 512 B ----------
// One wave per node; lane owns 4 cols (8 B). Per edge: readlane -> scalar row
// -> one global_load_dwordx2 with SGPR base (contiguous 8 lines, fully used).
// 16 loads batched per group for MLP. Full 16-groups are unconditional (zero
// padding waste); <=15-edge tail handled per-edge with scalar row index.
__launch_bounds__(256)
__global__ void gather_kernel(const unsigned short* __restrict__ hs,
                              const int2* __restrict__ meta,
                              const float* __restrict__ rnorm,
                              const int* __restrict__ csr,
                              float* __restrict__ out, int n) {
  const int wave = threadIdx.x >> 6;
  const int lane = threadIdx.x & 63;
  const int node = blockIdx.x * 4 + wave;
  if (node >= n) return;
  long long mm = __builtin_nontemporal_load((const long long*)&meta[node]);
  const int start = (int)mm;
  const int cnt = (int)(mm >> 32);
  const int loff = lane << 2;   // ushort offset within row: lane*4 cols = 8 B

  float a0 = 0.f, a1 = 0.f, a2 = 0.f, a3 = 0.f;

#define GRP16(G)                                                          \
  {                                                                       \
    u32x2 v[16];                                                          \
    _Pragma("unroll")                                                     \
    for (int u = 0; u < 16; ++u) {                                        \
      int r = __builtin_amdgcn_readlane(idxv, (G) + u);                   \
      v[u] = *(const u32x2*)&hs[((size_t)r << 8) + loff];                 \
    }                                                                     \
    _Pragma("unroll")                                                     \
    for (int u = 0; u < 16; ++u) {                                        \
      a0 += bf2f((unsigned short)v[u][0]);                                \
      a1 += bf2f((unsigned short)(v[u][0] >> 16));                        \
      a2 += bf2f((unsigned short)v[u][1]);                                \
      a3 += bf2f((unsigned short)(v[u][1] >> 16));                        \
    }                                                                     \
  }

  // csr is padded by 64 entries, so the chunk loads below never fault.
  int idxv = __builtin_nontemporal_load(&csr[start + lane]);
  int base = 0;
  while (base + 64 <= cnt) {
    int idxn = __builtin_nontemporal_load(&csr[start + base + 64 + lane]);
    GRP16(0) GRP16(16) GRP16(32) GRP16(48)
    idxv = idxn;
    base += 64;
  }
  int m = cnt - base;           // 0..63 remaining, already staged in idxv
  int g = 0;
  for (; g + 16 <= m; g += 16) GRP16(g)
  for (; g < m; ++g) {
    int r = __builtin_amdgcn_readlane(idxv, g);
    u32x2 v = *(const u32x2*)&hs[((size_t)r << 8) + loff];
    a0 += bf2f((unsigned short)v[0]);
    a1 += bf2f((unsigned short)(v[0] >> 16));
    a2 += bf2f((unsigned short)v[1]);
    a3 += bf2f((unsigned short)(v[1] >> 16));
  }
#undef GRP16

  // self term + final scale
  u32x2 us = *(const u32x2*)&hs[((size_t)node << 8) + loff];
  float rn = __builtin_nontemporal_load(&rnorm[node]);
  f32x4 o;
  o[0] = rn * (a0 + bf2f((unsigned short)us[0]));
  o[1] = rn * (a1 + bf2f((unsigned short)(us[0] >> 16)));
  o[2] = rn * (a2 + bf2f((unsigned short)us[1]));
  o[3] = rn * (a3 + bf2f((unsigned short)(us[1] >> 16)));
  __builtin_nontemporal_store(o, (f32x4*)&out[(size_t)node * 256 + loff]);
}

extern "C" void kernel_launch(void* const* d_in, const int* in_sizes, int n_in,
                              void* d_out, int out_size, void* d_ws, size_t ws_size,
                              hipStream_t stream) {
  const float* x = (const float*)d_in[0];
  const float* W = (const float*)d_in[1];
  const int* ei = (const int*)d_in[2];
  float* out = (float*)d_out;

  int N = in_sizes[0] / D;        // 100000
  int E = in_sizes[2] / 2;        // 3200000
  int NPAD = (N + 127) & ~127;
  const int* src = ei;
  const int* dst = ei + E;

  char* p = (char*)d_ws;
  auto alloc = [&](size_t b) {
    char* r = p;
    p += (b + 255) & ~(size_t)255;
    return r;
  };
  unsigned short* xb = (unsigned short*)alloc((size_t)NPAD * D * 2);
  unsigned short* wb = (unsigned short*)alloc((size_t)D * D * 2);
  unsigned short* hb = (unsigned short*)alloc((size_t)NPAD * D * 2);
  int* csr = (int*)alloc((size_t)(E + 64) * 4);   // +64 pad: chunk loads never fault
  int2* meta = (int2*)alloc((size_t)N * 8);
  float* rnorm = (float*)alloc((size_t)N * 4);
  int* bcount = (int*)alloc(NBUCK * 4);
  int* bbase = (int*)alloc(NBUCK * 4);
  int* gcursor = (int*)alloc(NBUCK * 4);
  // ebuf (E*4 = 12.8 MB) aliases hb (51 MB): dead before gemm writes hb
  int* ebuf = (int*)hb;

  hipMemsetAsync(bcount, 0, NBUCK * 4, stream);
  bucket_hist_kernel<<<256, 256, 0, stream>>>(src, bcount, E);
  bucket_scan_kernel<<<1, 512, 0, stream>>>(bcount, bbase, gcursor);
  binscatter_kernel<<<(E + TILE - 1) / TILE, 256, 0, stream>>>(src, dst, gcursor, ebuf, E);
  bucketsort_kernel<<<NBUCK, 256, 0, stream>>>(ebuf, bbase, bcount, csr, meta, rnorm, N);
  convx_kernel<<<(NPAD * (D / 4) + 255) / 256, 256, 0, stream>>>(x, xb, N, NPAD);
  convw_kernel<<<(D * D / 4) / 256, 256, 0, stream>>>(W, wb);
  gemm_kernel<<<dim3(NPAD / 128, D / 128), 256, 0, stream>>>(xb, wb, hb, rnorm, N);
  gather_kernel<<<(N + 3) / 4, 256, 0, stream>>>(hb, meta, rnorm, csr, out, N);
}